// Round 1
// baseline (324.845 us; speedup 1.0000x reference)
//
#include <hip/hip_runtime.h>
#include <hip/hip_bf16.h>

// ---------------------------------------------------------------------------
// Int8-quantized 3x3 conv, stride 1, pad 1.
//   x: (32,128,56,56) f32   w: (256,128,3,3) f32   bias: (256,) f32
//   out: (32,256,56,56) f32
// Pipeline: absmax(x), absmax(w) -> quantize (rintf(v/scale), clip +-127)
//           -> implicit GEMM conv with mfma_i32_16x16x64_i8 -> dequant+bias.
// ---------------------------------------------------------------------------

typedef int v4i __attribute__((ext_vector_type(4)));

#define NBATCH 32
#define CIN    128
#define HW     56
#define PIX    (HW*HW)            // 3136
#define COUT   256
#define XTOT   (NBATCH*CIN*PIX)   // 12,845,056
#define WTOT   (COUT*CIN*9)       // 294,912

// ---------------- ws init (ws is poisoned 0xAA before every launch) --------
__global__ void zero_ws_kernel(unsigned* p) {
    if (threadIdx.x < 2) p[threadIdx.x] = 0u;
}

// ---------------- abs-max reduction (bits of non-negative f32 order as u32) -
__global__ void absmax_kernel(const float* __restrict__ in, int n4, unsigned* out) {
    const float4* in4 = (const float4*)in;
    float m = 0.f;
    int stride = gridDim.x * blockDim.x;
    for (int i = blockIdx.x * blockDim.x + threadIdx.x; i < n4; i += stride) {
        float4 v = in4[i];
        m = fmaxf(m, fmaxf(fmaxf(fabsf(v.x), fabsf(v.y)),
                           fmaxf(fabsf(v.z), fabsf(v.w))));
    }
#pragma unroll
    for (int off = 32; off >= 1; off >>= 1)
        m = fmaxf(m, __shfl_xor(m, off, 64));
    if ((threadIdx.x & 63) == 0)
        atomicMax(out, __float_as_uint(m));
}

__device__ __forceinline__ float scale_from_bits(unsigned bits) {
    return fmaxf(__uint_as_float(bits) / 127.0f, 1e-8f);
}

// ---------------- quantize weights into [khw][o][c] int8 --------------------
__global__ void quant_w_kernel(const float* __restrict__ w,
                               const unsigned* __restrict__ mx,
                               signed char* __restrict__ qw) {
    float s = scale_from_bits(mx[1]);
    int idx = blockIdx.x * blockDim.x + threadIdx.x;
    if (idx >= WTOT) return;
    int o   = idx / (CIN * 9);
    int rem = idx % (CIN * 9);
    int c   = rem / 9;
    int khw = rem % 9;
    float q = rintf(w[idx] / s);
    q = fminf(127.0f, fmaxf(-127.0f, q));
    qw[khw * (COUT * CIN) + o * CIN + c] = (signed char)(int)q;
}

// ---------------- quantize x: NCHW f32 -> NHWC int8 (LDS transpose) ---------
__global__ __launch_bounds__(256) void quant_x_kernel(const float* __restrict__ x,
                                                      const unsigned* __restrict__ mx,
                                                      signed char* __restrict__ qx) {
    __shared__ signed char lds[32 * 132];   // 32 pixels x 128 c, row pad 132
    float s = scale_from_bits(mx[0]);
    const int n   = blockIdx.y;
    const int p0  = blockIdx.x * 32;
    const int tid = threadIdx.x;
#pragma unroll
    for (int i = 0; i < 16; ++i) {
        int idx = i * 256 + tid;          // 4096 = 128c x 32p
        int c   = idx >> 5;
        int pp  = idx & 31;
        float v = x[((size_t)(n * CIN + c)) * PIX + p0 + pp];
        float q = rintf(v / s);
        q = fminf(127.0f, fmaxf(-127.0f, q));
        lds[pp * 132 + c] = (signed char)(int)q;
    }
    __syncthreads();
#pragma unroll
    for (int i = 0; i < 4; ++i) {
        int idx = i * 256 + tid;          // 1024 int4-words
        int pp  = idx >> 5;
        int cw  = (idx & 31) * 4;
        *(int*)&qx[((size_t)(n * PIX + p0 + pp)) * CIN + cw] =
            *(const int*)&lds[pp * 132 + cw];
    }
}

// ---------------- conv: implicit GEMM, 64 px x 256 ch per block -------------
// A tile: qx rows [p0-57, p0+134] (192 rows x 128B) staged once in LDS,
// XOR-swizzled (byte ^= (row&7)<<4) so stride-128 ds_read_b128 is conflict-free.
// B fragments read directly from L2-resident qw. Padding via per-lane masks.
__global__ __launch_bounds__(256) void conv_kernel(
    const signed char* __restrict__ qx,
    const signed char* __restrict__ qw,
    const float* __restrict__ bias,
    const unsigned* __restrict__ mx,
    float* __restrict__ out)
{
    __shared__ signed char lds[192 * 128];   // 24.6 KB
    const int tid  = threadIdx.x;
    const int lane = tid & 63;
    const int wid  = tid >> 6;
    const int prow = lane & 15;   // A row / B col within fragment
    const int klo  = lane >> 4;   // K sub-chunk 0..3 (x16 bytes)

    const int m0 = blockIdx.x * 64;          // 1568 blocks, never cross images
    const int n  = m0 / PIX;
    const int p0 = m0 % PIX;

    // ---- stage A (once; no barriers afterwards in the K loop) ----
    const size_t xbase = (size_t)n * PIX * CIN;
#pragma unroll
    for (int it = 0; it < 6; ++it) {
        int chunk = it * 256 + tid;          // 1536 chunks of 16B
        int r  = chunk >> 3;                 // LDS row 0..191
        int cb = (chunk & 7) * 16;           // physical byte col
        int p  = p0 - 57 + r;                // global pixel (may be OOB)
        p = min(max(p, 0), PIX - 1);         // clamp; masked at use
        v4i v = *(const v4i*)(qx + xbase + (size_t)p * CIN + (cb ^ ((r & 7) << 4)));
        *(v4i*)&lds[r * 128 + cb] = v;
    }
    __syncthreads();

    v4i acc[4][4] = {};
    const v4i vzero = {0, 0, 0, 0};

    // per-sub-tile pixel coords (hoisted)
    int hh[4], ww[4], rbase[4];
#pragma unroll
    for (int s = 0; s < 4; ++s) {
        int i = s * 16 + prow;
        int p = p0 + i;
        hh[s] = p / HW;
        ww[s] = p % HW;
        rbase[s] = i + 57;
    }

#pragma unroll
    for (int dh = -1; dh <= 1; ++dh) {
#pragma unroll
        for (int dw = -1; dw <= 1; ++dw) {
            const int khw = (dh + 1) * 3 + (dw + 1);
            const signed char* bsrc = qw + (size_t)khw * (COUT * CIN);
#pragma unroll
            for (int kc = 0; kc < 2; ++kc) {
                const int col = kc * 64 + klo * 16;
                v4i b[4];
#pragma unroll
                for (int t = 0; t < 4; ++t) {
                    int ch = wid * 64 + t * 16 + prow;
                    b[t] = *(const v4i*)(bsrc + (size_t)ch * CIN + col);
                }
                v4i a[4];
#pragma unroll
                for (int s = 0; s < 4; ++s) {
                    bool valid = ((unsigned)(hh[s] + dh) < (unsigned)HW) &&
                                 ((unsigned)(ww[s] + dw) < (unsigned)HW);
                    int r = rbase[s] + dh * HW + dw;
                    v4i av = *(const v4i*)&lds[r * 128 + (col ^ ((r & 7) << 4))];
                    a[s] = valid ? av : vzero;
                }
#pragma unroll
                for (int s = 0; s < 4; ++s)
#pragma unroll
                    for (int t = 0; t < 4; ++t)
                        acc[s][t] = __builtin_amdgcn_mfma_i32_16x16x64_i8(
                            a[s], b[t], acc[s][t], 0, 0, 0);
            }
        }
    }

    // ---- epilogue: dequant + bias, float4 stores (4 consecutive pixels) ----
    const float comb = scale_from_bits(mx[0]) * scale_from_bits(mx[1]);
    const size_t obase = (size_t)n * COUT * PIX;
#pragma unroll
    for (int t = 0; t < 4; ++t) {
        int ch = wid * 64 + t * 16 + prow;
        float bs = bias[ch];
#pragma unroll
        for (int s = 0; s < 4; ++s) {
            int p = p0 + s * 16 + klo * 4;
            float4 v;
            v.x = (float)acc[s][t].x * comb + bs;
            v.y = (float)acc[s][t].y * comb + bs;
            v.z = (float)acc[s][t].z * comb + bs;
            v.w = (float)acc[s][t].w * comb + bs;
            *(float4*)&out[obase + (size_t)ch * PIX + p] = v;
        }
    }
}

// ---------------------------------------------------------------------------
extern "C" void kernel_launch(void* const* d_in, const int* in_sizes, int n_in,
                              void* d_out, int out_size, void* d_ws, size_t ws_size,
                              hipStream_t stream) {
    const float* x    = (const float*)d_in[0];
    const float* w    = (const float*)d_in[1];
    const float* bias = (const float*)d_in[2];
    float* out = (float*)d_out;

    // ws layout: [0..7] absmax bits (x, w); qx at +256 (12.85 MB); qw after.
    unsigned*    mx = (unsigned*)d_ws;
    signed char* qx = (signed char*)d_ws + 256;
    signed char* qw = qx + (size_t)XTOT;

    zero_ws_kernel<<<1, 64, 0, stream>>>(mx);
    absmax_kernel<<<2048, 256, 0, stream>>>(x, XTOT / 4, mx + 0);
    absmax_kernel<<<288, 256, 0, stream>>>(w, WTOT / 4, mx + 1);
    quant_w_kernel<<<(WTOT + 255) / 256, 256, 0, stream>>>(w, mx, qw);
    quant_x_kernel<<<dim3(98, 32), 256, 0, stream>>>(x, mx, qx);
    conv_kernel<<<1568, 256, 0, stream>>>(qx, qw, bias, mx, out);
}

// Round 3
// 226.338 us; speedup vs baseline: 1.4352x; 1.4352x over previous
//
#include <hip/hip_runtime.h>
#include <hip/hip_bf16.h>

// ---------------------------------------------------------------------------
// Int8-quantized 3x3 conv, stride 1, pad 1.
//   x: (32,128,56,56) f32   w: (256,128,3,3) f32   bias: (256,) f32
//   out: (32,256,56,56) f32
// Pipeline: absmax partials (no atomics) -> finalize scales -> quantize
//           -> implicit GEMM conv with mfma_i32_16x16x64_i8 -> dequant+bias.
// R1 lesson: 8192 same-address atomicMax = 106 us (13 ns/atomic cross-XCD
// serialization). Replaced with block partials + 1-block finalize.
// R2: broker timeout, no data; identical resubmission.
// ---------------------------------------------------------------------------

typedef int v4i __attribute__((ext_vector_type(4)));

#define NBATCH 32
#define CIN    128
#define HW     56
#define PIX    (HW*HW)            // 3136
#define COUT   256
#define XTOT   (NBATCH*CIN*PIX)   // 12,845,056
#define WTOT   (COUT*CIN*9)       // 294,912

// ---------------- abs-max partials: one plain store per block ---------------
template <int ITERS>
__global__ __launch_bounds__(256) void absmax_part_kernel(
    const float* __restrict__ in, float* __restrict__ partial)
{
    const float4* in4 = (const float4*)in;
    const int t      = blockIdx.x * 256 + threadIdx.x;
    const int stride = gridDim.x * 256;
    float m = 0.f;
#pragma unroll
    for (int k = 0; k < ITERS; ++k) {
        float4 v = in4[t + k * stride];
        m = fmaxf(m, fmaxf(fmaxf(fabsf(v.x), fabsf(v.y)),
                           fmaxf(fabsf(v.z), fabsf(v.w))));
    }
#pragma unroll
    for (int off = 32; off >= 1; off >>= 1)
        m = fmaxf(m, __shfl_xor(m, off, 64));
    __shared__ float wmax[4];
    const int lane = threadIdx.x & 63, wid = threadIdx.x >> 6;
    if (lane == 0) wmax[wid] = m;
    __syncthreads();
    if (threadIdx.x == 0)
        partial[blockIdx.x] =
            fmaxf(fmaxf(wmax[0], wmax[1]), fmaxf(wmax[2], wmax[3]));
}

// ---------------- finalize: reduce partials -> scales (1 block) -------------
__global__ __launch_bounds__(256) void finalize_kernel(
    const float* __restrict__ px, const float* __restrict__ pw,
    float* __restrict__ scales)
{
    const int tid = threadIdx.x;
    float mxv = 0.f, mwv = 0.f;
#pragma unroll
    for (int k = 0; k < 4; ++k) {
        int i = k * 256 + tid;
        if (i < 896) mxv = fmaxf(mxv, px[i]);
    }
    if (tid < 72) mwv = pw[tid];
#pragma unroll
    for (int off = 32; off >= 1; off >>= 1) {
        mxv = fmaxf(mxv, __shfl_xor(mxv, off, 64));
        mwv = fmaxf(mwv, __shfl_xor(mwv, off, 64));
    }
    __shared__ float sx[4], sw[4];
    const int lane = tid & 63, wid = tid >> 6;
    if (lane == 0) { sx[wid] = mxv; sw[wid] = mwv; }
    __syncthreads();
    if (tid == 0) {
        float fx = fmaxf(fmaxf(sx[0], sx[1]), fmaxf(sx[2], sx[3]));
        float fw = fmaxf(fmaxf(sw[0], sw[1]), fmaxf(sw[2], sw[3]));
        scales[0] = fmaxf(fx / 127.0f, 1e-8f);
        scales[1] = fmaxf(fw / 127.0f, 1e-8f);
    }
}

// ---------------- quantize weights into [khw][o][c] int8 --------------------
__global__ void quant_w_kernel(const float* __restrict__ w,
                               const float* __restrict__ scales,
                               signed char* __restrict__ qw) {
    float s = scales[1];
    int idx = blockIdx.x * blockDim.x + threadIdx.x;
    if (idx >= WTOT) return;
    int o   = idx / (CIN * 9);
    int rem = idx % (CIN * 9);
    int c   = rem / 9;
    int khw = rem % 9;
    float q = rintf(w[idx] / s);
    q = fminf(127.0f, fmaxf(-127.0f, q));
    qw[khw * (COUT * CIN) + o * CIN + c] = (signed char)(int)q;
}

// ---------------- quantize x: NCHW f32 -> NHWC int8 (float4 loads) ----------
__global__ __launch_bounds__(256) void quant_x_kernel(const float* __restrict__ x,
                                                      const float* __restrict__ scales,
                                                      signed char* __restrict__ qx) {
    __shared__ signed char lds[32 * 132];   // 32 pixels x 128 c, row pad 132
    float s = scales[0];
    const int n   = blockIdx.y;
    const int p0  = blockIdx.x * 32;
    const int tid = threadIdx.x;
#pragma unroll
    for (int i = 0; i < 4; ++i) {
        int idx = i * 256 + tid;          // 1024 float4 = 128c x 8 pixel-quads
        int c   = idx >> 3;
        int pq  = idx & 7;
        float4 v = *(const float4*)&x[((size_t)(n * CIN + c)) * PIX + p0 + pq * 4];
        float qv[4] = {v.x, v.y, v.z, v.w};
#pragma unroll
        for (int j = 0; j < 4; ++j) {
            float q = rintf(qv[j] / s);
            q = fminf(127.0f, fmaxf(-127.0f, q));
            lds[(pq * 4 + j) * 132 + c] = (signed char)(int)q;
        }
    }
    __syncthreads();
#pragma unroll
    for (int i = 0; i < 4; ++i) {
        int idx = i * 256 + tid;          // 1024 int4-words
        int pp  = idx >> 5;
        int cw  = (idx & 31) * 4;
        *(int*)&qx[((size_t)(n * PIX + p0 + pp)) * CIN + cw] =
            *(const int*)&lds[pp * 132 + cw];
    }
}

// ---------------- conv: implicit GEMM, 64 px x 256 ch per block -------------
// A tile: qx rows [p0-57, p0+134] (192 rows x 128B) staged once in LDS,
// XOR-swizzled (byte ^= (row&7)<<4) so stride-128 ds_read_b128 is conflict-free.
// B fragments read directly from L2-resident qw. Padding via per-lane masks.
__global__ __launch_bounds__(256) void conv_kernel(
    const signed char* __restrict__ qx,
    const signed char* __restrict__ qw,
    const float* __restrict__ bias,
    const float* __restrict__ scales,
    float* __restrict__ out)
{
    __shared__ signed char lds[192 * 128];   // 24.6 KB
    const int tid  = threadIdx.x;
    const int lane = tid & 63;
    const int wid  = tid >> 6;
    const int prow = lane & 15;   // A row / B col within fragment
    const int klo  = lane >> 4;   // K sub-chunk 0..3 (x16 bytes)

    const int m0 = blockIdx.x * 64;          // 1568 blocks, never cross images
    const int n  = m0 / PIX;
    const int p0 = m0 % PIX;

    // ---- stage A (once; no barriers afterwards in the K loop) ----
    const size_t xbase = (size_t)n * PIX * CIN;
#pragma unroll
    for (int it = 0; it < 6; ++it) {
        int chunk = it * 256 + tid;          // 1536 chunks of 16B
        int r  = chunk >> 3;                 // LDS row 0..191
        int cb = (chunk & 7) * 16;           // physical byte col
        int p  = p0 - 57 + r;                // global pixel (may be OOB)
        p = min(max(p, 0), PIX - 1);         // clamp; masked at use
        v4i v = *(const v4i*)(qx + xbase + (size_t)p * CIN + (cb ^ ((r & 7) << 4)));
        *(v4i*)&lds[r * 128 + cb] = v;
    }
    __syncthreads();

    v4i acc[4][4] = {};
    const v4i vzero = {0, 0, 0, 0};

    // per-sub-tile pixel coords (hoisted)
    int hh[4], ww[4], rbase[4];
#pragma unroll
    for (int s = 0; s < 4; ++s) {
        int i = s * 16 + prow;
        int p = p0 + i;
        hh[s] = p / HW;
        ww[s] = p % HW;
        rbase[s] = i + 57;
    }

#pragma unroll
    for (int dh = -1; dh <= 1; ++dh) {
#pragma unroll
        for (int dw = -1; dw <= 1; ++dw) {
            const int khw = (dh + 1) * 3 + (dw + 1);
            const signed char* bsrc = qw + (size_t)khw * (COUT * CIN);
#pragma unroll
            for (int kc = 0; kc < 2; ++kc) {
                const int col = kc * 64 + klo * 16;
                v4i b[4];
#pragma unroll
                for (int t = 0; t < 4; ++t) {
                    int ch = wid * 64 + t * 16 + prow;
                    b[t] = *(const v4i*)(bsrc + (size_t)ch * CIN + col);
                }
                v4i a[4];
#pragma unroll
                for (int s = 0; s < 4; ++s) {
                    bool valid = ((unsigned)(hh[s] + dh) < (unsigned)HW) &&
                                 ((unsigned)(ww[s] + dw) < (unsigned)HW);
                    int r = rbase[s] + dh * HW + dw;
                    v4i av = *(const v4i*)&lds[r * 128 + (col ^ ((r & 7) << 4))];
                    a[s] = valid ? av : vzero;
                }
#pragma unroll
                for (int s = 0; s < 4; ++s)
#pragma unroll
                    for (int t = 0; t < 4; ++t)
                        acc[s][t] = __builtin_amdgcn_mfma_i32_16x16x64_i8(
                            a[s], b[t], acc[s][t], 0, 0, 0);
            }
        }
    }

    // ---- epilogue: dequant + bias, float4 stores (4 consecutive pixels) ----
    const float comb = scales[0] * scales[1];
    const size_t obase = (size_t)n * COUT * PIX;
#pragma unroll
    for (int t = 0; t < 4; ++t) {
        int ch = wid * 64 + t * 16 + prow;
        float bs = bias[ch];
#pragma unroll
        for (int s = 0; s < 4; ++s) {
            int p = p0 + s * 16 + klo * 4;
            float4 v;
            v.x = (float)acc[s][t].x * comb + bs;
            v.y = (float)acc[s][t].y * comb + bs;
            v.z = (float)acc[s][t].z * comb + bs;
            v.w = (float)acc[s][t].w * comb + bs;
            *(float4*)&out[obase + (size_t)ch * PIX + p] = v;
        }
    }
}

// ---------------------------------------------------------------------------
extern "C" void kernel_launch(void* const* d_in, const int* in_sizes, int n_in,
                              void* d_out, int out_size, void* d_ws, size_t ws_size,
                              hipStream_t stream) {
    const float* x    = (const float*)d_in[0];
    const float* w    = (const float*)d_in[1];
    const float* bias = (const float*)d_in[2];
    float* out = (float*)d_out;

    // ws layout: scales (2 f32) at 0; partials_x (896 f32) at +1KB;
    // partials_w (72 f32) at +4.6KB; qx at +8KB (12.85 MB); qw after.
    float*       scales = (float*)d_ws;
    float*       px     = (float*)((char*)d_ws + 1024);
    float*       pw     = (float*)((char*)d_ws + 4608);
    signed char* qx     = (signed char*)d_ws + 8192;
    signed char* qw     = qx + (size_t)XTOT;

    // x: 12,845,056 f32 = 3,211,264 float4 = 896 blocks x 256 thr x 14 iters
    absmax_part_kernel<14><<<896, 256, 0, stream>>>(x, px);
    // w: 294,912 f32 = 73,728 float4 = 72 blocks x 256 thr x 4 iters
    absmax_part_kernel<4><<<72, 256, 0, stream>>>(w, pw);
    finalize_kernel<<<1, 256, 0, stream>>>(px, pw, scales);
    quant_w_kernel<<<WTOT / 256, 256, 0, stream>>>(w, scales, qw);
    quant_x_kernel<<<dim3(98, 32), 256, 0, stream>>>(x, scales, qx);
    conv_kernel<<<1568, 256, 0, stream>>>(qx, qw, bias, scales, out);
}

// Round 5
// 217.913 us; speedup vs baseline: 1.4907x; 1.0387x over previous
//
#include <hip/hip_runtime.h>
#include <hip/hip_bf16.h>

// ---------------------------------------------------------------------------
// Int8-quantized 3x3 conv, stride 1, pad 1.
//   x: (32,128,56,56) f32   w: (256,128,3,3) f32   bias: (256,) f32
//   out: (32,256,56,56) f32
// R1 lesson: same-address atomicMax = 106 us -> block partials.
// R3 lesson: conv latency-bound (occ 17%: VGPR92+AGPR64=156/wave -> 2 waves/
//   SIMD; serial B-load->MFMA chain; 16 cndmask/step). Fix: acc[4][2] tile
//   (64px x 128ch, grid 3136), explicit B double-buffer, zero-padded 2D LDS
//   tile (no per-step masks).
// R4 lesson: backend bug — v_mul_f32 with TWO SGPR operands (constant-bus
//   violation) from scales[0]*scales[1]; force one factor into a VGPR via
//   empty inline-asm "+v".
// ---------------------------------------------------------------------------

typedef int v4i __attribute__((ext_vector_type(4)));

#define NBATCH 32
#define CIN    128
#define HW     56
#define PIX    (HW*HW)            // 3136
#define COUT   256
#define XTOT   (NBATCH*CIN*PIX)   // 12,845,056
#define WTOT   (COUT*CIN*9)       // 294,912

// ---------------- abs-max partials: one plain store per block ---------------
template <int ITERS>
__global__ __launch_bounds__(256) void absmax_part_kernel(
    const float* __restrict__ in, float* __restrict__ partial)
{
    const float4* in4 = (const float4*)in;
    const int t      = blockIdx.x * 256 + threadIdx.x;
    const int stride = gridDim.x * 256;
    float m = 0.f;
#pragma unroll
    for (int k = 0; k < ITERS; ++k) {
        float4 v = in4[t + k * stride];
        m = fmaxf(m, fmaxf(fmaxf(fabsf(v.x), fabsf(v.y)),
                           fmaxf(fabsf(v.z), fabsf(v.w))));
    }
#pragma unroll
    for (int off = 32; off >= 1; off >>= 1)
        m = fmaxf(m, __shfl_xor(m, off, 64));
    __shared__ float wmax[4];
    const int lane = threadIdx.x & 63, wid = threadIdx.x >> 6;
    if (lane == 0) wmax[wid] = m;
    __syncthreads();
    if (threadIdx.x == 0)
        partial[blockIdx.x] =
            fmaxf(fmaxf(wmax[0], wmax[1]), fmaxf(wmax[2], wmax[3]));
}

// ---------------- finalize: reduce partials -> scales (1 block) -------------
__global__ __launch_bounds__(256) void finalize_kernel(
    const float* __restrict__ px, const float* __restrict__ pw,
    float* __restrict__ scales)
{
    const int tid = threadIdx.x;
    float mxv = 0.f, mwv = 0.f;
#pragma unroll
    for (int k = 0; k < 7; ++k)
        mxv = fmaxf(mxv, px[k * 256 + tid]);   // 1792 partials exactly
    if (tid < 72) mwv = pw[tid];
#pragma unroll
    for (int off = 32; off >= 1; off >>= 1) {
        mxv = fmaxf(mxv, __shfl_xor(mxv, off, 64));
        mwv = fmaxf(mwv, __shfl_xor(mwv, off, 64));
    }
    __shared__ float sx[4], sw[4];
    const int lane = tid & 63, wid = tid >> 6;
    if (lane == 0) { sx[wid] = mxv; sw[wid] = mwv; }
    __syncthreads();
    if (tid == 0) {
        float fx = fmaxf(fmaxf(sx[0], sx[1]), fmaxf(sx[2], sx[3]));
        float fw = fmaxf(fmaxf(sw[0], sw[1]), fmaxf(sw[2], sw[3]));
        scales[0] = fmaxf(fx / 127.0f, 1e-8f);
        scales[1] = fmaxf(fw / 127.0f, 1e-8f);
    }
}

// ---------------- quantize weights into [khw][o][c] int8 --------------------
__global__ void quant_w_kernel(const float* __restrict__ w,
                               const float* __restrict__ scales,
                               signed char* __restrict__ qw) {
    float s = scales[1];
    int idx = blockIdx.x * blockDim.x + threadIdx.x;
    if (idx >= WTOT) return;
    int o   = idx / (CIN * 9);
    int rem = idx % (CIN * 9);
    int c   = rem / 9;
    int khw = rem % 9;
    float q = rintf(w[idx] / s);
    q = fminf(127.0f, fmaxf(-127.0f, q));
    qw[khw * (COUT * CIN) + o * CIN + c] = (signed char)(int)q;
}

// ---------------- quantize x: NCHW f32 -> NHWC int8 (float4 loads) ----------
__global__ __launch_bounds__(256) void quant_x_kernel(const float* __restrict__ x,
                                                      const float* __restrict__ scales,
                                                      signed char* __restrict__ qx) {
    __shared__ signed char lds[32 * 132];   // 32 pixels x 128 c, row pad 132
    float s = scales[0];
    const int n   = blockIdx.y;
    const int p0  = blockIdx.x * 32;
    const int tid = threadIdx.x;
#pragma unroll
    for (int i = 0; i < 4; ++i) {
        int idx = i * 256 + tid;          // 1024 float4 = 128c x 8 pixel-quads
        int c   = idx >> 3;
        int pq  = idx & 7;
        float4 v = *(const float4*)&x[((size_t)(n * CIN + c)) * PIX + p0 + pq * 4];
        float qv[4] = {v.x, v.y, v.z, v.w};
#pragma unroll
        for (int j = 0; j < 4; ++j) {
            float q = rintf(qv[j] / s);
            q = fminf(127.0f, fmaxf(-127.0f, q));
            lds[(pq * 4 + j) * 132 + c] = (signed char)(int)q;
        }
    }
    __syncthreads();
#pragma unroll
    for (int i = 0; i < 4; ++i) {
        int idx = i * 256 + tid;          // 1024 int4-words
        int pp  = idx >> 5;
        int cw  = (idx & 31) * 4;
        *(int*)&qx[((size_t)(n * PIX + p0 + pp)) * CIN + cw] =
            *(const int*)&lds[pp * 132 + cw];
    }
}

// ---------------- conv: implicit GEMM, 64 px x 128 ch per block -------------
// A: zero-padded 2D tile [4 h-rows][58 w][128B] in LDS (29 KB), XOR-swizzled
//    (byte ^= (r&7)<<4). Padding baked as zeros -> no masking in K-loop.
// B: per-step fragments from L2-resident qw, explicit double-buffer (load
//    st+1 before st's MFMAs).
// 4 waves, wave = 64px x 32ch, acc[4][2] = 32 AGPR. Target VGPR+AGPR <= 128.
__global__ __launch_bounds__(256, 4) void conv_kernel(
    const signed char* __restrict__ qx,
    const signed char* __restrict__ qw,
    const float* __restrict__ bias,
    const float* __restrict__ scales,
    float* __restrict__ out)
{
    __shared__ signed char lds[232 * 128];   // 29,696 B
    const int tid  = threadIdx.x;
    const int lane = tid & 63;
    const int wid  = tid >> 6;     // 0..3
    const int prow = lane & 15;    // fragment row (pixel for A, channel for B)
    const int klo  = lane >> 4;    // K sub-chunk (x16B)

    const int bid = blockIdx.x;    // 3136 blocks
    const int nh  = bid & 1;       // channel half; pairs share the A-tile
    const int mt  = bid >> 1;      // 0..1567
    const int n   = mt / 49;
    const int p0  = (mt % 49) * 64;
    const int hbase = p0 / HW - 1;

    const size_t xbase = (size_t)n * PIX * CIN;

    // ---- stage A: 232 LDS-rows (4 h x 58 w) x 128B, zeros in pads ----
#pragma unroll
    for (int it = 0; it < 8; ++it) {
        int chunk = it * 256 + tid;            // 1856 chunks of 16B
        if (chunk < 232 * 8) {
            int r  = chunk >> 3;
            int cb = (chunk & 7) * 16;
            int hr = r / 58;
            int wc = r - hr * 58;
            int h  = hbase + hr;
            int w  = wc - 1;
            bool valid = ((unsigned)h < HW) && ((unsigned)w < HW);
            int p = valid ? (h * HW + w) : 0;  // clamped addr, value masked
            v4i v = *(const v4i*)(qx + xbase + (size_t)p * CIN + cb);
            if (!valid) v = (v4i){0, 0, 0, 0};
            *(v4i*)&lds[r * 128 + (cb ^ ((r & 7) << 4))] = v;
        }
    }
    __syncthreads();

    // per-s LDS row base (dh=0, dw=0)
    int rr[4];
#pragma unroll
    for (int s = 0; s < 4; ++s) {
        int p = p0 + s * 16 + prow;
        int h = p / HW, w = p - h * HW;
        rr[s] = (h - hbase) * 58 + (w + 1);
    }

    const int ch0     = nh * 128 + wid * 32;
    const int colbase = klo * 16;

    v4i acc[4][2] = {};

    // B fragment address for step st (t=0); t=1 adds 16*CIN
    const signed char* b0ptr = qw + (size_t)(ch0 + prow) * CIN + colbase;
#define BADDR(st) (b0ptr + (size_t)((st) >> 1) * (COUT * CIN) + ((st) & 1) * 64)

    v4i bcur0 = *(const v4i*)BADDR(0);
    v4i bcur1 = *(const v4i*)(BADDR(0) + 16 * CIN);

#pragma unroll
    for (int st = 0; st < 18; ++st) {
        v4i bn0 = bcur0, bn1 = bcur1;
        if (st < 17) {                          // prefetch next step's B
            const signed char* bp = BADDR(st + 1);
            bn0 = *(const v4i*)bp;
            bn1 = *(const v4i*)(bp + 16 * CIN);
        }
        const int khw  = st >> 1;
        const int rofs = (khw / 3 - 1) * 58 + (khw % 3 - 1);
        const int col  = (st & 1) * 64 + colbase;
        v4i a[4];
#pragma unroll
        for (int s = 0; s < 4; ++s) {
            int r = rr[s] + rofs;
            a[s] = *(const v4i*)&lds[r * 128 + (col ^ ((r & 7) << 4))];
        }
#pragma unroll
        for (int s = 0; s < 4; ++s) {
            acc[s][0] = __builtin_amdgcn_mfma_i32_16x16x64_i8(a[s], bcur0, acc[s][0], 0, 0, 0);
            acc[s][1] = __builtin_amdgcn_mfma_i32_16x16x64_i8(a[s], bcur1, acc[s][1], 0, 0, 0);
        }
        bcur0 = bn0; bcur1 = bn1;
    }
#undef BADDR

    // ---- epilogue: dequant + bias, float4 stores ----
    float s0 = scales[0], s1 = scales[1];
    asm volatile("" : "+v"(s0));   // force VGPR: two-SGPR v_mul is illegal
    const float comb = s0 * s1;
    const size_t obase = (size_t)n * COUT * PIX;
#pragma unroll
    for (int t = 0; t < 2; ++t) {
        int ch = ch0 + t * 16 + prow;
        float bs = bias[ch];
#pragma unroll
        for (int s = 0; s < 4; ++s) {
            int p = p0 + s * 16 + klo * 4;
            float4 v;
            v.x = (float)acc[s][t].x * comb + bs;
            v.y = (float)acc[s][t].y * comb + bs;
            v.z = (float)acc[s][t].z * comb + bs;
            v.w = (float)acc[s][t].w * comb + bs;
            *(float4*)&out[obase + (size_t)ch * PIX + p] = v;
        }
    }
}

// ---------------------------------------------------------------------------
extern "C" void kernel_launch(void* const* d_in, const int* in_sizes, int n_in,
                              void* d_out, int out_size, void* d_ws, size_t ws_size,
                              hipStream_t stream) {
    const float* x    = (const float*)d_in[0];
    const float* w    = (const float*)d_in[1];
    const float* bias = (const float*)d_in[2];
    float* out = (float*)d_out;

    // ws layout: scales (2 f32) @0; px (1792 f32) @256; pw (72 f32) @7680;
    // qx @8192 (12.85 MB); qw after.
    float*       scales = (float*)d_ws;
    float*       px     = (float*)((char*)d_ws + 256);
    float*       pw     = (float*)((char*)d_ws + 7680);
    signed char* qx     = (signed char*)d_ws + 8192;
    signed char* qw     = qx + (size_t)XTOT;

    // x: 3,211,264 float4 = 1792 blocks x 256 thr x 7 iters (exact)
    absmax_part_kernel<7><<<1792, 256, 0, stream>>>(x, px);
    // w: 73,728 float4 = 72 blocks x 256 thr x 4 iters (exact)
    absmax_part_kernel<4><<<72, 256, 0, stream>>>(w, pw);
    finalize_kernel<<<1, 256, 0, stream>>>(px, pw, scales);
    quant_w_kernel<<<WTOT / 256, 256, 0, stream>>>(w, scales, qw);
    quant_x_kernel<<<dim3(98, 32), 256, 0, stream>>>(x, scales, qx);
    conv_kernel<<<3136, 256, 0, stream>>>(qx, qw, bias, scales, out);
}